// Round 10
// baseline (83.748 us; speedup 1.0000x reference)
//
#include <hip/hip_runtime.h>
#include <math.h>

#define HIDDEN 1024
#define NL 9
#define LEAN_TAU 0.25f
#define LEAN_DELTA 0.35f
#define LCH 16  // CRF scan chunk length

typedef __attribute__((ext_vector_type(8))) short short8v;  // 8 x bf16 frag
typedef __attribute__((ext_vector_type(4))) float f32x4;    // C/D frag

__device__ inline unsigned short f2b(float x) {  // fp32 -> bf16 (RNE)
  unsigned u = __float_as_uint(x);
  return (unsigned short)((u + 0x7fffu + ((u >> 16) & 1u)) >> 16);
}

// ---------------- Kernel 1: emission logits via MFMA + lean adjust ----------
// One 16-token tile per wave. A = hs tile (16x1024) staged fp32->bf16 through
// per-wave private LDS (4 phases of K=256; padded rows -> <=2-way bank
// conflicts, free). B = w^T in 32 register fragments (cols 9..15 zero).
// 32 x mfma_f32_16x16x32_bf16 replace the 54-shfl/token reduce (R5-R9's
// model-resistant 60-90us tail). C/D: col=lane&15(label), row=(lane>>4)*4+reg
// (m89-verified). Top-2 via 4-step 16-lane butterfly on pre-adjust values.
__global__ __launch_bounds__(256, 2) void logits_mfma(
    const float* __restrict__ hs, const float* __restrict__ w,
    const float* __restrict__ bias, const int* __restrict__ amask,
    float* __restrict__ e, int B, int T) {
  const int TOK = T - 2, nTok = B * TOK;
  const int nTile = (nTok + 15) >> 4;
  const int wave = threadIdx.x >> 6, lane = threadIdx.x & 63;
  const int g = lane >> 4, c = lane & 15;
  __shared__ unsigned short aT[4][16][264];  // per-wave [row][256+8 pad] bf16

  const int tile = blockIdx.x * 4 + wave;
  if (tile >= nTile) return;  // no barriers anywhere -> early exit safe

  // ---- B fragments (w^T, bf16) in registers, built once per wave ----
  short8v bfrag[32];
  {
    const int csafe = (c < NL) ? c : 0;
    const float* wr = w + (size_t)csafe * HIDDEN + g * 8;
#pragma unroll
    for (int s = 0; s < 32; ++s) {
      const float4 u0 = *reinterpret_cast<const float4*>(wr + 32 * s);
      const float4 u1 = *reinterpret_cast<const float4*>(wr + 32 * s + 4);
      short8v bb;
      if (c < NL) {
        bb[0] = f2b(u0.x); bb[1] = f2b(u0.y); bb[2] = f2b(u0.z); bb[3] = f2b(u0.w);
        bb[4] = f2b(u1.x); bb[5] = f2b(u1.y); bb[6] = f2b(u1.z); bb[7] = f2b(u1.w);
      } else {
#pragma unroll
        for (int i = 0; i < 8; ++i) bb[i] = 0;
      }
      bfrag[s] = bb;
    }
  }

  // ---- per-row global base offsets (consecutive tokens, batch-aware) ----
  unsigned rowoff[16];
#pragma unroll
  for (int r = 0; r < 16; ++r) {
    int tok = tile * 16 + r;
    if (tok >= nTok) tok = nTok - 1;
    const int b = tok / TOK, t = tok - b * TOK;
    rowoff[r] = ((unsigned)b * T + t + 1) * HIDDEN;
  }

  f32x4 acc = {0.f, 0.f, 0.f, 0.f};
#pragma unroll
  for (int ph = 0; ph < 4; ++ph) {
    // stage 16 rows x 256 floats -> bf16 LDS (two 8-row batches for MLP)
#pragma unroll
    for (int bt = 0; bt < 2; ++bt) {
      float4 f[8];
#pragma unroll
      for (int rr = 0; rr < 8; ++rr)
        f[rr] = *reinterpret_cast<const float4*>(
            hs + rowoff[bt * 8 + rr] + ph * 256 + lane * 4);
#pragma unroll
      for (int rr = 0; rr < 8; ++rr) {
        uint2 pk;
        pk.x = (unsigned)f2b(f[rr].x) | ((unsigned)f2b(f[rr].y) << 16);
        pk.y = (unsigned)f2b(f[rr].z) | ((unsigned)f2b(f[rr].w) << 16);
        *reinterpret_cast<uint2*>(&aT[wave][bt * 8 + rr][lane * 4]) = pk;
      }
    }
    // 8 MFMA steps over this K=256 phase
#pragma unroll
    for (int sl = 0; sl < 8; ++sl) {
      const short8v a = *reinterpret_cast<const short8v*>(
          &aT[wave][c][g * 8 + sl * 32]);
      acc = __builtin_amdgcn_mfma_f32_16x16x32_bf16(a, bfrag[ph * 8 + sl],
                                                    acc, 0, 0, 0);
    }
  }

  // ---- epilogue: bias, top-2 (pre-adjust), lean, store ----
  const float bc = (c < NL) ? bias[c] : 0.f;
#pragma unroll
  for (int j = 0; j < 4; ++j) {
    const int r = g * 4 + j;
    const int tok = tile * 16 + r;
    const int tokc = (tok < nTok) ? tok : 0;
    const int b = tokc / TOK, t = tokc - b * TOK;
    const float v = acc[j] + bc;
    float m1 = (c < NL) ? v : -1e30f, m2 = -1e30f;
#pragma unroll
    for (int off = 1; off < 16; off <<= 1) {
      const float om1 = __shfl_xor(m1, off);
      const float om2 = __shfl_xor(m2, off);
      const float hi = fmaxf(m1, om1);
      const float lo = fminf(m1, om1);
      m2 = fmaxf(lo, fmaxf(m2, om2));
      m1 = hi;
    }
    const bool unc = (m1 - m2 < LEAN_TAU) && (amask[b * T + t + 1] != 0);
    const float vout = v + ((unc && c == 0) ? LEAN_DELTA : 0.f);
    if (c < NL && tok < nTok) e[(size_t)tok * NL + c] = vout;
  }
}

// ---------------- Kernel 2: per-chunk log-space matrix products ----------------
// 7 chunks per wave; lane = sub*9 + i holds row i of chunk sub's 9x9 product.
// Factored logsumexp: W = exp(trans) in registers -> 9 exp + 9 log + 81 fma/step.
__global__ __launch_bounds__(64) void chunk_k(
    const float* __restrict__ e, const int* __restrict__ labels,
    const float* __restrict__ trans, float* __restrict__ Pout,
    int B, int T, int C) {
  const int TOK = T - 2;
  __shared__ float e2[7][LCH][NL];
  __shared__ float tr2[NL * NL];
  __shared__ int msk[7][LCH];
  const int tid = threadIdx.x;
  const int nG = B * C;
  const int gbase = blockIdx.x * 7;

  for (int idx = tid; idx < NL * NL; idx += 64) tr2[idx] = trans[idx];
  for (int idx = tid; idx < 7 * LCH * NL; idx += 64) {
    const int sub = idx / (LCH * NL), rem = idx % (LCH * NL);
    const int step = rem / NL, j = rem % NL;
    const int g = gbase + sub;
    if (g < nG) {
      const int b = g / C, c = g % C;
      const int t = 1 + c * LCH + step;
      if (t < TOK) e2[sub][step][j] = e[((size_t)b * TOK + t) * NL + j];
    }
  }
  for (int idx = tid; idx < 7 * LCH; idx += 64) {
    const int sub = idx / LCH, step = idx % LCH;
    const int g = gbase + sub;
    if (g < nG) {
      const int b = g / C, c = g % C;
      const int t = 1 + c * LCH + step;
      msk[sub][step] = (t < TOK) ? (labels[(size_t)b * T + 1 + t] != -100) : 0;
    }
  }
  __syncthreads();

  const int sub = tid / NL, i = tid % NL;  // sub==7 only for tid 63 (inactive)
  const int g = gbase + sub;
  const bool act = (sub < 7) && (g < nG);
  int len = 1;
  if (act) { const int c = g % C; len = min(LCH, TOK - (1 + c * LCH)); }

  float W[NL][NL];
#pragma unroll
  for (int k = 0; k < NL; ++k)
#pragma unroll
    for (int j = 0; j < NL; ++j) W[k][j] = __expf(tr2[k * NL + j]);

  float P[NL];
  {
    const int m0 = act ? msk[sub][0] : 0;
#pragma unroll
    for (int j = 0; j < NL; ++j)
      P[j] = m0 ? (tr2[i * NL + j] + e2[sub][0][j])
                : ((i == j) ? 0.f : -1e30f);
  }
  for (int step = 1; step < len; ++step) {
    const int mt = msk[sub][step];
    float mx = P[0];
#pragma unroll
    for (int k = 1; k < NL; ++k) mx = fmaxf(mx, P[k]);
    float E[NL];
#pragma unroll
    for (int k = 0; k < NL; ++k) E[k] = __expf(P[k] - mx);
    float Pn[NL];
#pragma unroll
    for (int j = 0; j < NL; ++j) {
      float s = 0.f;
#pragma unroll
      for (int k = 0; k < NL; ++k) s = fmaf(E[k], W[k][j], s);
      Pn[j] = mx + __logf(s) + e2[sub][step][j];
    }
#pragma unroll
    for (int j = 0; j < NL; ++j) P[j] = mt ? Pn[j] : P[j];
  }
  if (act) {
    float* dst = Pout + (size_t)g * 81 + i * NL;
#pragma unroll
    for (int j = 0; j < NL; ++j) dst[j] = P[j];
  }
}

// ---------------- Kernel 3: per-batch combine (num + den fold) ----------------
__global__ __launch_bounds__(64) void combine_k(
    const float* __restrict__ e, const int* __restrict__ labels,
    const float* __restrict__ start_t, const float* __restrict__ end_t,
    const float* __restrict__ trans, const float* __restrict__ Pmat,
    float* __restrict__ llh, int B, int T, int C) {
  const int TOK = T - 2;
  const int b = blockIdx.x, lane = threadIdx.x;
  const float* eb = e + (size_t)b * TOK * NL;
  const int* lb = labels + (size_t)b * T + 1;

  // ---- numerator: chain-free, data-parallel over t ----
  const int g0r = lb[0];
  const int tg0 = (g0r == -100) ? 0 : g0r;
  float nsum = 0.f;
  int pack = -1;  // (t<<4)|tag of last masked step
  for (int t = 1 + lane; t < TOK; t += 64) {
    const int gr = lb[t], pr = lb[t - 1];
    if (gr != -100) {
      const int cur = gr;
      const int prev = (pr == -100) ? 0 : pr;
      nsum += trans[prev * NL + cur] + eb[t * NL + cur];
      pack = (t << 4) | cur;
    }
  }
#pragma unroll
  for (int off = 32; off; off >>= 1) {
    nsum += __shfl_xor(nsum, off);
    pack = max(pack, __shfl_xor(pack, off));
  }
  const int last = (pack < 0) ? tg0 : (pack & 15);
  const float num = start_t[tg0] + eb[tg0] + nsum + end_t[last];

  // ---- denominator: fold C chunk matrices ----
  float alpha = (lane < NL) ? (start_t[lane] + eb[lane]) : -1e30f;
  for (int c = 0; c < C; ++c) {
    const float* Pc = Pmat + ((size_t)b * C + c) * 81;
    float col[NL];
#pragma unroll
    for (int i = 0; i < NL; ++i)
      col[i] = (lane < NL) ? Pc[i * NL + lane] : -1e30f;
    float s[NL];
    float mx = -1e30f;
#pragma unroll
    for (int i = 0; i < NL; ++i) {
      const float ai = __shfl(alpha, i);
      s[i] = ai + col[i];
      mx = fmaxf(mx, s[i]);
    }
    float sum = 0.f;
#pragma unroll
    for (int i = 0; i < NL; ++i) sum += __expf(s[i] - mx);
    const float nx = mx + __logf(sum);
    alpha = (lane < NL) ? nx : -1e30f;
  }
  const float v = (lane < NL) ? (alpha + end_t[lane]) : -1e30f;
  float mx = v;
#pragma unroll
  for (int off = 32; off; off >>= 1) mx = fmaxf(mx, __shfl_xor(mx, off));
  float sum = (lane < NL) ? __expf(v - mx) : 0.f;
#pragma unroll
  for (int off = 32; off; off >>= 1) sum += __shfl_xor(sum, off);
  const float den = mx + __logf(sum);
  if (lane == 0) llh[b] = num - den;
}

// ---------------- Kernel 4: -mean(llh) ----------------
__global__ __launch_bounds__(64) void reduce_k(const float* __restrict__ llh,
                                               float* __restrict__ out, int B) {
  float v = 0.f;
  for (int i = threadIdx.x; i < B; i += 64) v += llh[i];
#pragma unroll
  for (int off = 32; off; off >>= 1) v += __shfl_xor(v, off);
  if (threadIdx.x == 0) out[0] = -v / (float)B;
}

extern "C" void kernel_launch(void* const* d_in, const int* in_sizes, int n_in,
                              void* d_out, int out_size, void* d_ws,
                              size_t ws_size, hipStream_t stream) {
  const float* hs     = (const float*)d_in[0];
  const float* w      = (const float*)d_in[1];
  const float* bias   = (const float*)d_in[2];
  const float* st     = (const float*)d_in[3];
  const float* et     = (const float*)d_in[4];
  const float* tr     = (const float*)d_in[5];
  const int*   amask  = (const int*)d_in[6];
  const int*   labels = (const int*)d_in[7];

  const int T = 512;
  const int B = in_sizes[6] / T;
  const int TOK = T - 2;
  const int C = (TOK - 1 + LCH - 1) / LCH;  // chunks of the 509 recurrence steps

  float* e    = (float*)d_ws;                 // (B, TOK, 9)
  float* llh  = e + (size_t)B * TOK * NL;     // (B,)
  float* Pmat = llh + B;                      // (B*C, 81)

  const int nTok = B * TOK;
  const int nTile = (nTok + 15) / 16;
  logits_mfma<<<(nTile + 3) / 4, 256, 0, stream>>>(hs, w, bias, amask, e, B, T);
  const int nG = B * C;
  chunk_k<<<(nG + 6) / 7, 64, 0, stream>>>(e, labels, tr, Pmat, B, T, C);
  combine_k<<<B, 64, 0, stream>>>(e, labels, st, et, tr, Pmat, llh, B, T, C);
  reduce_k<<<1, 64, 0, stream>>>(llh, (float*)d_out, B);
}